// Round 7
// baseline (829.102 us; speedup 1.0000x reference)
//
#include <hip/hip_runtime.h>

#define GH 135
#define GW 240
#define HH 1080
#define WW 1920
#define HWPX (HH*WW)
#define NP 12
#define IT 4               // anchor block-rows per WG (i-strip)
#define JT 12              // anchor blocks (j) per WG
#define NBG 6              // anchor pairs per it-row
#define NIG 34             // ceil(GH/IT)
#define NJG 20             // GW/JT
#define TROWS (IT+8)       // 12 staged target block-rows
#define TBLK (JT+8)        // 20 staged target blocks per dy-row
#define DSTR (TBLK*64+4)   // 1284 dw: 16B-aligned; dr*1284 %32 = 4*dr (quad shift per row)
#define UNITS_ROW (TBLK*16)// 320 16B-units per dy-row
#define UNITS_TOT (TROWS*UNITS_ROW) // 3840
#define NTHR 512
#define NACT 432           // 9 dy * (4 it * 6 bg * 2 yh)
#define TT_DW (TROWS*DSTR) // 15408 dw = 61632 B -> 2 WG/CU (16 waves, 4/SIMD)
#define NWG (NIG*NJG)      // 680 = 8*85 (XCD-exact)

// Swizzled storage (bijective involution, proven r5):
//   stored(blk, y, xh) = blk*64 + ((y*8+xh) ^ 4*kb ^ 16*yh),  kb=(blk>>1)&7, yh=y>>2
// Write side LINEAR (zero write conflicts); global src inverse-swizzled.
// r6 lesson: NO register prefetch (13xfloat4 spilled -> 600MB scratch traffic).
// This round's lever is geometry: 4 waves/SIMD + 40% less halo per anchor.

// 8-px fp32 chain + f64 accumulate (argmin-exact vs np reference, proven r1-r6)
#define CHAIN(AV0, AV1, T0, T1, ACC) do { \
    float _d = (AV0).x - (T0).x; float _s = _d*_d; \
    _d = (AV0).y - (T0).y; _s = fmaf(_d,_d,_s); \
    _d = (AV0).z - (T0).z; _s = fmaf(_d,_d,_s); \
    _d = (AV0).w - (T0).w; _s = fmaf(_d,_d,_s); \
    _d = (AV1).x - (T1).x; _s = fmaf(_d,_d,_s); \
    _d = (AV1).y - (T1).y; _s = fmaf(_d,_d,_s); \
    _d = (AV1).z - (T1).z; _s = fmaf(_d,_d,_s); \
    _d = (AV1).w - (T1).w; _s = fmaf(_d,_d,_s); \
    (ACC) += (double)_s; } while(0)

__global__ void __launch_bounds__(NTHR, 4)
hbma_cost_kernel(const float* __restrict__ A, const float* __restrict__ T,
                 int* __restrict__ bestidx) {
    extern __shared__ float lds[];
    float* Tt = lds;

    // XCD swizzle: 680 WGs = 8 XCDs x 85; per-XCD consecutive pos -> consecutive ig
    const int lin = blockIdx.x;
    const int g   = (lin & 7) * (NWG / 8) + (lin >> 3);
    const int ig  = g % NIG, jg = g / NIG;
    const int i0  = ig * IT;
    const int j0  = jg * JT;

    const int tid = threadIdx.x;
    const int dy  = tid / 48;          // 0..8 for active threads
    const int rem = tid % 48;
    const int it  = rem / 12;          // 0..3
    const int r2  = rem % 12;
    const int bg  = r2 >> 1;           // 0..5 (anchor pair)
    const int yh  = r2 & 1;            // y-half
    const bool act = (tid < NACT);
    const int i   = i0 + it;           // may be >= GH on last strip (guarded)
    const int gi  = i + dy - 4;
    const bool dyValid = act && (i < GH) && (gi >= 0) && (gi < GH);
    const int dr  = it + dy;           // staged row index 0..11

    int xq[5];                         // per p-pair h: 4*((bg+h)&7) ^ 16*yh
#pragma unroll
    for (int h = 0; h < 5; ++h) xq[h] = (((bg + h) & 7) * 4) ^ (yh << 4);

    double acc0[9], acc1[9];
#pragma unroll
    for (int d = 0; d < 9; ++d) { acc0[d] = 0.0; acc1[d] = 0.0; }

    const int gy0 = (i0 - 4) * 8;
    const int gx0 = (j0 - 4) * 8;

    for (int q = 0; q < NP; ++q) {
        const float* Tq = T + (size_t)q * HWPX;
        const float* Aq = A + (size_t)q * HWPX;
        __syncthreads();               // prev compute done before LDS overwrite
        // ---- stage target halo: LINEAR LDS writes, inverse-swizzled global src ----
        for (int w = tid; w < UNITS_TOT; w += NTHR) {
            const int dyr = w / UNITS_ROW;
            const int u   = w - dyr * UNITS_ROW;    // 16B unit within dy-row
            const int blk = u >> 4, v = u & 15;
            const int kb  = (blk >> 1) & 7;
            const int yh2 = v >> 3;
            const int m3  = (v & 7) ^ kb ^ (yh2 << 2);
            const int y   = (yh2 << 2) + (m3 >> 1);
            const int xh4 = m3 & 1;
            const int gy  = gy0 + dyr * 8 + y;
            const int gx  = gx0 + blk * 8 + xh4 * 4;
            if ((unsigned)gy < (unsigned)HH && (unsigned)gx < (unsigned)WW) {
                *(float4*)(Tt + dyr * DSTR + u * 4) =
                    *(const float4*)(Tq + (size_t)gy * WW + gx);
            }
        }
        // ---- anchor rows -> registers (global; 9x dy-redundant -> L1-hot) ----
        float4 ar[2][4][2];
        if (act && i < GH) {
#pragma unroll
            for (int a2 = 0; a2 < 2; ++a2) {
                const float* ap = Aq + (size_t)(j0 + 2 * bg + a2) * 8;
#pragma unroll
                for (int yi = 0; yi < 4; ++yi) {
                    const float* row = ap + (size_t)(i * 8 + yh * 4 + yi) * WW;
                    ar[a2][yi][0] = *(const float4*)(row);
                    ar[a2][yi][1] = *(const float4*)(row + 4);
                }
            }
        }
        __syncthreads();
        // ---- SSD: sliding 10-block window serves 2 anchors x 9 dx ----
        if (dyValid) {
            const float* tb = Tt + dr * DSTR + bg * 128 + yh * 32;
#pragma unroll
            for (int yi = 0; yi < 4; ++yi) {
#pragma unroll
                for (int ph = 0; ph < 2; ++ph) {       // p-chunks of 5: 10-deep ds ILP
                    float4 tw0[5], tw1[5];
#pragma unroll
                    for (int pp = 0; pp < 5; ++pp) {
                        const int p  = ph * 5 + pp;
                        const int o0 = (yi * 8) ^ xq[p >> 1];
                        tw0[pp] = *(const float4*)(tb + p * 64 + o0);
                        tw1[pp] = *(const float4*)(tb + p * 64 + (o0 ^ 4));
                    }
#pragma unroll
                    for (int pp = 0; pp < 5; ++pp) {
                        const int p = ph * 5 + pp;
                        if (p < 9) CHAIN(ar[0][yi][0], ar[0][yi][1], tw0[pp], tw1[pp], acc0[p]);
                        if (p > 0) CHAIN(ar[1][yi][0], ar[1][yi][1], tw0[pp], tw1[pp], acc1[p - 1]);
                    }
                }
            }
        }
    }
    // ---- y-half merge via LDS (aliases Tt, barrier-protected) ----
    __syncthreads();
    double* yred = (double*)lds;                     // 216 pairs * 18 f64 = 7776 dw
    const int pairId = (it * NBG + bg) * 9 + dy;
    if (act && yh == 1) {
        double* d = yred + pairId * 18;
#pragma unroll
        for (int k = 0; k < 9; ++k) { d[k] = acc0[k]; d[9 + k] = acc1[k]; }
    }
    __syncthreads();
    double* redc = (double*)(lds + 8192);            // 432 f64 = 864 dw
    int*    redk = (int*)(lds + 8192 + 864);         // 432 int
    if (act && yh == 0) {
        const double* d = yred + pairId * 18;
#pragma unroll
        for (int k = 0; k < 9; ++k) { acc0[k] += d[k]; acc1[k] += d[9 + k]; }
        // stage-1 argmin over dx (ascending, strict < -> first-k ties)
#pragma unroll
        for (int a2 = 0; a2 < 2; ++a2) {
            double bc = 1e300; int bk = -1;
            const int jb = j0 + 2 * bg + a2;
#pragma unroll
            for (int dxi = 0; dxi < 9; ++dxi) {
                const int gj = jb + dxi - 4;
                const double c = a2 ? acc1[dxi] : acc0[dxi];
                if (dyValid && gj >= 0 && gj < GW && c < bc) { bc = c; bk = dy * 9 + dxi; }
            }
            redc[(it * 9 + dy) * JT + 2 * bg + a2] = bc;
            redk[(it * 9 + dy) * JT + 2 * bg + a2] = bk;
        }
    }
    __syncthreads();
    // ---- stage-2 argmin over dy (ascending, strict <) ----
    if (tid < IT * JT) {
        const int it2 = tid / JT, jt = tid % JT;
        if (i0 + it2 < GH) {
            double c = 1e300; int k = -1;
#pragma unroll
            for (int dyi = 0; dyi < 9; ++dyi) {
                const double v = redc[(it2 * 9 + dyi) * JT + jt];
                if (v < c) { c = v; k = redk[(it2 * 9 + dyi) * JT + jt]; }
            }
            const int dyi = k / 9, dxi = k % 9;
            const int bi = i0 + it2 + dyi - 4;
            const int bj = j0 + jt + dxi - 4;
            bestidx[(i0 + it2) * GW + j0 + jt] = (bi << 8) | bj;
        }
    }
}

__global__ void __launch_bounds__(256) hbma_gather_kernel(const float* __restrict__ A,
                                                          const int* __restrict__ bestidx,
                                                          float* __restrict__ out) {
    const int tid = blockIdx.x * 256 + threadIdx.x;
    const int q   = tid / (HWPX / 4);
    const int rem = tid % (HWPX / 4);
    const int py  = rem / (WW / 4);
    const int c4  = rem % (WW / 4);
    const int i = py >> 3, y = py & 7;
    const int j = c4 >> 1, xh = (c4 & 1) * 4;
    const int idx = bestidx[i * GW + j];
    const int bi = idx >> 8, bj = idx & 255;
    const float4 v = *(const float4*)(A + (size_t)q * HWPX + (size_t)(bi * 8 + y) * WW + bj * 8 + xh);
    *(float4*)(out + (size_t)q * HWPX + (size_t)py * WW + c4 * 4) = v;
}

extern "C" void kernel_launch(void* const* d_in, const int* in_sizes, int n_in,
                              void* d_out, int out_size, void* d_ws, size_t ws_size,
                              hipStream_t stream) {
    const float* A = (const float*)d_in[0];
    const float* T = (const float*)d_in[1];
    float* out = (float*)d_out;
    int* bestidx = (int*)d_ws;

    hipFuncSetAttribute((const void*)hbma_cost_kernel,
                        hipFuncAttributeMaxDynamicSharedMemorySize, TT_DW * 4);

    hipLaunchKernelGGL(hbma_cost_kernel, dim3(NWG), dim3(NTHR), TT_DW * 4, stream,
                       A, T, bestidx);

    const int total4 = (NP * HWPX) / 4;
    hipLaunchKernelGGL(hbma_gather_kernel, dim3(total4 / 256), dim3(256), 0, stream,
                       A, bestidx, out);
}

// Round 8
// 346.487 us; speedup vs baseline: 2.3929x; 2.3929x over previous
//
#include <hip/hip_runtime.h>

#define GH 135
#define GW 240
#define HH 1080
#define WW 1920
#define HWPX (HH*WW)
#define NP 12
#define IT 4               // anchor block-rows per WG (i-strip)
#define JT 12              // anchor blocks (j) per WG
#define NBG 6              // anchor pairs per it-row
#define NIG 34             // ceil(GH/IT)
#define NJG 20             // GW/JT
#define TROWS (IT+8)       // 12 staged target block-rows
#define TBLK (JT+8)        // 20 staged target blocks per dy-row
#define DSTR (TBLK*64+4)   // 1284 dw: 16B-aligned; dr*1284 %32 = 4*dr (quad shift per row)
#define UNITS_ROW (TBLK*16)// 320 16B-units per dy-row
#define UNITS_TOT (TROWS*UNITS_ROW) // 3840
#define NTHR 512
#define NACT 432           // 9 dy * (4 it * 6 bg * 2 yh)
#define TT_DW (TROWS*DSTR) // 15408 dw = 61632 B -> 2 WG/CU (16 waves, 4/SIMD)
#define NWG (NIG*NJG)      // 680 = 8*85 (XCD-exact)

// Swizzled storage (bijective involution, proven r5):
//   stored(blk, y, xh) = blk*64 + ((y*8+xh) ^ 4*kb ^ 16*yh),  kb=(blk>>1)&7, yh=y>>2
// Write side LINEAR (zero write conflicts); global src inverse-swizzled.
// r6 lesson: NO register prefetch (13xfloat4 spilled -> 600MB scratch traffic).
// r7 lesson: __launch_bounds__(512,4) capped VGPRs at 64 -> f64 accumulators
// spilled (WRITE_SIZE 1.1GB). (512,2) gives the allocator >=128 VGPRs; real
// occupancy is LDS-bound at 2 WG/CU (16 waves, 4/SIMD) regardless.

// 8-px fp32 chain + f64 accumulate (argmin-exact vs np reference, proven r1-r7)
#define CHAIN(AV0, AV1, T0, T1, ACC) do { \
    float _d = (AV0).x - (T0).x; float _s = _d*_d; \
    _d = (AV0).y - (T0).y; _s = fmaf(_d,_d,_s); \
    _d = (AV0).z - (T0).z; _s = fmaf(_d,_d,_s); \
    _d = (AV0).w - (T0).w; _s = fmaf(_d,_d,_s); \
    _d = (AV1).x - (T1).x; _s = fmaf(_d,_d,_s); \
    _d = (AV1).y - (T1).y; _s = fmaf(_d,_d,_s); \
    _d = (AV1).z - (T1).z; _s = fmaf(_d,_d,_s); \
    _d = (AV1).w - (T1).w; _s = fmaf(_d,_d,_s); \
    (ACC) += (double)_s; } while(0)

__global__ void __launch_bounds__(NTHR, 2)
hbma_cost_kernel(const float* __restrict__ A, const float* __restrict__ T,
                 int* __restrict__ bestidx) {
    extern __shared__ float lds[];
    float* Tt = lds;

    // XCD swizzle: 680 WGs = 8 XCDs x 85; per-XCD consecutive pos -> consecutive ig
    const int lin = blockIdx.x;
    const int g   = (lin & 7) * (NWG / 8) + (lin >> 3);
    const int ig  = g % NIG, jg = g / NIG;
    const int i0  = ig * IT;
    const int j0  = jg * JT;

    const int tid = threadIdx.x;
    const int dy  = tid / 48;          // 0..8 for active threads
    const int rem = tid % 48;
    const int it  = rem / 12;          // 0..3
    const int r2  = rem % 12;
    const int bg  = r2 >> 1;           // 0..5 (anchor pair)
    const int yh  = r2 & 1;            // y-half
    const bool act = (tid < NACT);
    const int i   = i0 + it;           // may be >= GH on last strip (guarded)
    const int gi  = i + dy - 4;
    const bool dyValid = act && (i < GH) && (gi >= 0) && (gi < GH);
    const int dr  = it + dy;           // staged row index 0..11

    int xq[5];                         // per p-pair h: 4*((bg+h)&7) ^ 16*yh
#pragma unroll
    for (int h = 0; h < 5; ++h) xq[h] = (((bg + h) & 7) * 4) ^ (yh << 4);

    double acc0[9], acc1[9];
#pragma unroll
    for (int d = 0; d < 9; ++d) { acc0[d] = 0.0; acc1[d] = 0.0; }

    const int gy0 = (i0 - 4) * 8;
    const int gx0 = (j0 - 4) * 8;

    for (int q = 0; q < NP; ++q) {
        const float* Tq = T + (size_t)q * HWPX;
        const float* Aq = A + (size_t)q * HWPX;
        __syncthreads();               // prev compute done before LDS overwrite
        // ---- stage target halo: LINEAR LDS writes, inverse-swizzled global src ----
        for (int w = tid; w < UNITS_TOT; w += NTHR) {
            const int dyr = w / UNITS_ROW;
            const int u   = w - dyr * UNITS_ROW;    // 16B unit within dy-row
            const int blk = u >> 4, v = u & 15;
            const int kb  = (blk >> 1) & 7;
            const int yh2 = v >> 3;
            const int m3  = (v & 7) ^ kb ^ (yh2 << 2);
            const int y   = (yh2 << 2) + (m3 >> 1);
            const int xh4 = m3 & 1;
            const int gy  = gy0 + dyr * 8 + y;
            const int gx  = gx0 + blk * 8 + xh4 * 4;
            if ((unsigned)gy < (unsigned)HH && (unsigned)gx < (unsigned)WW) {
                *(float4*)(Tt + dyr * DSTR + u * 4) =
                    *(const float4*)(Tq + (size_t)gy * WW + gx);
            }
        }
        // ---- anchor rows -> registers (global; 9x dy-redundant -> L1-hot) ----
        float4 ar[2][4][2];
        if (act && i < GH) {
#pragma unroll
            for (int a2 = 0; a2 < 2; ++a2) {
                const float* ap = Aq + (size_t)(j0 + 2 * bg + a2) * 8;
#pragma unroll
                for (int yi = 0; yi < 4; ++yi) {
                    const float* row = ap + (size_t)(i * 8 + yh * 4 + yi) * WW;
                    ar[a2][yi][0] = *(const float4*)(row);
                    ar[a2][yi][1] = *(const float4*)(row + 4);
                }
            }
        }
        __syncthreads();
        // ---- SSD: sliding 10-block window serves 2 anchors x 9 dx ----
        if (dyValid) {
            const float* tb = Tt + dr * DSTR + bg * 128 + yh * 32;
#pragma unroll
            for (int yi = 0; yi < 4; ++yi) {
#pragma unroll
                for (int ph = 0; ph < 2; ++ph) {       // p-chunks of 5: 10-deep ds ILP
                    float4 tw0[5], tw1[5];
#pragma unroll
                    for (int pp = 0; pp < 5; ++pp) {
                        const int p  = ph * 5 + pp;
                        const int o0 = (yi * 8) ^ xq[p >> 1];
                        tw0[pp] = *(const float4*)(tb + p * 64 + o0);
                        tw1[pp] = *(const float4*)(tb + p * 64 + (o0 ^ 4));
                    }
#pragma unroll
                    for (int pp = 0; pp < 5; ++pp) {
                        const int p = ph * 5 + pp;
                        if (p < 9) CHAIN(ar[0][yi][0], ar[0][yi][1], tw0[pp], tw1[pp], acc0[p]);
                        if (p > 0) CHAIN(ar[1][yi][0], ar[1][yi][1], tw0[pp], tw1[pp], acc1[p - 1]);
                    }
                }
            }
        }
    }
    // ---- y-half merge via LDS (aliases Tt, barrier-protected) ----
    __syncthreads();
    double* yred = (double*)lds;                     // 216 pairs * 18 f64 = 7776 dw
    const int pairId = (it * NBG + bg) * 9 + dy;
    if (act && yh == 1) {
        double* d = yred + pairId * 18;
#pragma unroll
        for (int k = 0; k < 9; ++k) { d[k] = acc0[k]; d[9 + k] = acc1[k]; }
    }
    __syncthreads();
    double* redc = (double*)(lds + 8192);            // 432 f64 = 864 dw
    int*    redk = (int*)(lds + 8192 + 864);         // 432 int
    if (act && yh == 0) {
        const double* d = yred + pairId * 18;
#pragma unroll
        for (int k = 0; k < 9; ++k) { acc0[k] += d[k]; acc1[k] += d[9 + k]; }
        // stage-1 argmin over dx (ascending, strict < -> first-k ties)
#pragma unroll
        for (int a2 = 0; a2 < 2; ++a2) {
            double bc = 1e300; int bk = -1;
            const int jb = j0 + 2 * bg + a2;
#pragma unroll
            for (int dxi = 0; dxi < 9; ++dxi) {
                const int gj = jb + dxi - 4;
                const double c = a2 ? acc1[dxi] : acc0[dxi];
                if (dyValid && gj >= 0 && gj < GW && c < bc) { bc = c; bk = dy * 9 + dxi; }
            }
            redc[(it * 9 + dy) * JT + 2 * bg + a2] = bc;
            redk[(it * 9 + dy) * JT + 2 * bg + a2] = bk;
        }
    }
    __syncthreads();
    // ---- stage-2 argmin over dy (ascending, strict <) ----
    if (tid < IT * JT) {
        const int it2 = tid / JT, jt = tid % JT;
        if (i0 + it2 < GH) {
            double c = 1e300; int k = -1;
#pragma unroll
            for (int dyi = 0; dyi < 9; ++dyi) {
                const double v = redc[(it2 * 9 + dyi) * JT + jt];
                if (v < c) { c = v; k = redk[(it2 * 9 + dyi) * JT + jt]; }
            }
            const int dyi = k / 9, dxi = k % 9;
            const int bi = i0 + it2 + dyi - 4;
            const int bj = j0 + jt + dxi - 4;
            bestidx[(i0 + it2) * GW + j0 + jt] = (bi << 8) | bj;
        }
    }
}

__global__ void __launch_bounds__(256) hbma_gather_kernel(const float* __restrict__ A,
                                                          const int* __restrict__ bestidx,
                                                          float* __restrict__ out) {
    const int tid = blockIdx.x * 256 + threadIdx.x;
    const int q   = tid / (HWPX / 4);
    const int rem = tid % (HWPX / 4);
    const int py  = rem / (WW / 4);
    const int c4  = rem % (WW / 4);
    const int i = py >> 3, y = py & 7;
    const int j = c4 >> 1, xh = (c4 & 1) * 4;
    const int idx = bestidx[i * GW + j];
    const int bi = idx >> 8, bj = idx & 255;
    const float4 v = *(const float4*)(A + (size_t)q * HWPX + (size_t)(bi * 8 + y) * WW + bj * 8 + xh);
    *(float4*)(out + (size_t)q * HWPX + (size_t)py * WW + c4 * 4) = v;
}

extern "C" void kernel_launch(void* const* d_in, const int* in_sizes, int n_in,
                              void* d_out, int out_size, void* d_ws, size_t ws_size,
                              hipStream_t stream) {
    const float* A = (const float*)d_in[0];
    const float* T = (const float*)d_in[1];
    float* out = (float*)d_out;
    int* bestidx = (int*)d_ws;

    hipFuncSetAttribute((const void*)hbma_cost_kernel,
                        hipFuncAttributeMaxDynamicSharedMemorySize, TT_DW * 4);

    hipLaunchKernelGGL(hbma_cost_kernel, dim3(NWG), dim3(NTHR), TT_DW * 4, stream,
                       A, T, bestidx);

    const int total4 = (NP * HWPX) / 4;
    hipLaunchKernelGGL(hbma_gather_kernel, dim3(total4 / 256), dim3(256), 0, stream,
                       A, bestidx, out);
}